// Round 12
// baseline (400.968 us; speedup 1.0000x reference)
//
#include <hip/hip_runtime.h>
#include <math.h>

typedef __attribute__((ext_vector_type(8))) short short8;
typedef __attribute__((ext_vector_type(4))) float floatx4;

__device__ inline float bf2f(short s) {
    union { unsigned u; float f; } x; x.u = ((unsigned)(unsigned short)s) << 16; return x.f;
}
__device__ inline short f2bf(float f) {
    union { float f; unsigned u; } x; x.f = f;
    unsigned r = x.u + 0x7fff + ((x.u >> 16) & 1);
    return (short)(r >> 16);
}
// pack 2 f32 -> 2 bf16 (RNE) in one instruction; lo = src0, hi = src1
__device__ inline unsigned cvtpk2(float a, float b) {
    unsigned r;
    asm("v_cvt_pk_bf16_f32 %0, %1, %2" : "=v"(r) : "v"(a), "v"(b));
    return r;
}

struct WSet {
    const float *fw1, *fb1, *fw2, *sw1, *sb1, *sw2, *sb2, *dw1, *db1, *dw2, *db2;
};

// ---------------- weight prep core ----------------
// W1f: [c 0..4][kc 0..11][g 0..15][lane][8]; m=c*256+g*16+(l&15) (0-pad >=1152), k=kc*32+(l>>4)*8+e
// W2af: [ka 0..15][g 0..7][lane][8] from fw2 [128x512]
// W2bf: [kb 0..23][g 0..7][lane][8]; r=g*16+(l&15): sw2 (r<64,krel<512) / dw2 (r==64,512<=krel<640) / 0
__device__ inline void wprep_core(const WSet A,
    short* __restrict__ W1f, short* __restrict__ W2af, short* __restrict__ W2bf,
    float* __restrict__ B1p, float* __restrict__ B2bp, int id)
{
    if (id < 491520) {
        int e = id & 7, l = (id >> 3) & 63, g = (id >> 9) & 15, rest = id >> 13;
        int kc = rest % 12, c = rest / 12;
        int m = c * 256 + g * 16 + (l & 15);
        int k = kc * 32 + (l >> 4) * 8 + e;
        float v = 0.f;
        if (m < 512) v = A.fw1[m * 384 + k];
        else if (m < 1024) v = A.sw1[(m - 512) * 384 + k];
        else if (m < 1152) v = A.dw1[(m - 1024) * 384 + k];
        W1f[id] = f2bf(v);
        return;
    }
    id -= 491520;
    if (id < 65536) {
        int e = id & 7, l = (id >> 3) & 63, g = (id >> 9) & 7, ka = id >> 12;
        int r = g * 16 + (l & 15), k = ka * 32 + (l >> 4) * 8 + e;
        W2af[id] = f2bf(A.fw2[r * 512 + k]);
        return;
    }
    id -= 65536;
    if (id < 98304) {
        int e = id & 7, l = (id >> 3) & 63, g = (id >> 9) & 7, kb = id >> 12;
        int r = g * 16 + (l & 15), krel = kb * 32 + (l >> 4) * 8 + e;
        float v = 0.f;
        if (r < 64 && krel < 512) v = A.sw2[r * 512 + krel];
        else if (r == 64 && krel >= 512 && krel < 640) v = A.dw2[krel - 512];
        W2bf[id] = f2bf(v);
        return;
    }
    id -= 98304;
    if (id < 1280) {
        float v = 0.f;
        if (id < 512) v = A.fb1[id];
        else if (id < 1024) v = A.sb1[id - 512];
        else if (id < 1152) v = A.db1[id - 1024];
        B1p[id] = v;
        return;
    }
    id -= 1280;
    if (id < 128) B2bp[id] = id < 64 ? A.sb2[id] : id == 64 ? A.db2[0] : 0.f;
}

// ---------------- xprep core (float4 x loads, cvt_pk packing) ----------------
__device__ inline void xprep_core(const float* __restrict__ x,
                                  short* __restrict__ xT, short* __restrict__ x1T,
                                  float* xt, int ip, int cg, int b, int t)
{
    #pragma unroll
    for (int u = 0; u < 8; u++) {
        int idx = t + 256 * u;             // 0..2047 float4 slots
        int c = idx >> 5, spq = idx & 31;  // sp = spq*4
        float4 v = *(const float4*)&x[(((long)b * 384 + cg * 64 + c) * 64 + ip * 2 + (spq >> 4)) * 64 + (spq & 15) * 4];
        float* d = &xt[c * 129 + spq * 4];
        d[0] = v.x; d[1] = v.y; d[2] = v.z; d[3] = v.w;
    }
    __syncthreads();
    {
        int sp = t >> 1, ch = t & 1;
        unsigned tmp[16];
        #pragma unroll
        for (int cc = 0; cc < 16; cc++)
            tmp[cc] = cvtpk2(xt[(ch * 32 + 2 * cc) * 129 + sp], xt[(ch * 32 + 2 * cc + 1) * 129 + sp]);
        short* dst = xT + ((long)b * 4096 + ip * 128 + sp) * 384 + cg * 64 + ch * 32;
        #pragma unroll
        for (int v = 0; v < 4; v++) *(short8*)(dst + v * 8) = *(short8*)(tmp + v * 4);
    }
    {
        int j1 = t >> 3, c8 = t & 7;
        unsigned tmp[4];
        #pragma unroll
        for (int e = 0; e < 4; e++) {
            int c = c8 * 8 + 2 * e;
            float v0 = 0.25f * (xt[c * 129 + j1 * 2]      + xt[c * 129 + j1 * 2 + 1] +
                                xt[c * 129 + 64 + j1 * 2] + xt[c * 129 + 64 + j1 * 2 + 1]);
            float v1 = 0.25f * (xt[(c + 1) * 129 + j1 * 2]      + xt[(c + 1) * 129 + j1 * 2 + 1] +
                                xt[(c + 1) * 129 + 64 + j1 * 2] + xt[(c + 1) * 129 + 64 + j1 * 2 + 1]);
            tmp[e] = cvtpk2(v0, v1);
        }
        *(short8*)(x1T + ((long)b * 1024 + ip * 32 + j1) * 384 + cg * 64 + c8 * 8) = *(short8*)tmp;
    }
}

// ---------------- standalone wprep / xprep (CB<16 fallback) ----------------
__global__ __launch_bounds__(256) void wprep(WSet a0, WSet a1,
    short* __restrict__ W1f, short* __restrict__ W2af, short* __restrict__ W2bf,
    float* __restrict__ B1p, float* __restrict__ B2bp)
{
    const int s = blockIdx.y;
    const WSet A = s ? a1 : a0;
    wprep_core(A, W1f + (size_t)s * 491520, W2af + (size_t)s * 65536,
               W2bf + (size_t)s * 98304, B1p + s * 1280, B2bp + s * 128,
               blockIdx.x * 256 + threadIdx.x);
}

__global__ __launch_bounds__(256) void xprep(const float* __restrict__ x,
                                             short* __restrict__ xT, short* __restrict__ x1T)
{
    __shared__ float xt[64 * 129];
    xprep_core(x, xT, x1T, xt, blockIdx.x, blockIdx.y, blockIdx.z, threadIdx.x);
}

// ---------------- prep2 (CB==16): xprep blocks (bx<32) + wprep blocks (bx>=32) ----------------
// wprep blocks also zero the dred fan-in counters each launch (replay-safe: graph replays
// rerun this dispatch before dred_fan).
__global__ __launch_bounds__(256) void prep2(WSet a0, WSet a1,
    short* __restrict__ W1f, short* __restrict__ W2af, short* __restrict__ W2bf,
    float* __restrict__ B1p, float* __restrict__ B2bp,
    const float* __restrict__ x, short* __restrict__ xT, short* __restrict__ x1T,
    unsigned* __restrict__ ctr)
{
    __shared__ float xt[64 * 129];
    const int bx = blockIdx.x, by = blockIdx.y, bz = blockIdx.z;
    const int t = threadIdx.x;
    if (bx >= 32) {
        const int slot = (bx - 32) + 54 * (by + 6 * bz);   // 0..5183
        if (slot == 0 && t < 16) ctr[t] = 0;
        const int s = slot >= 2566;
        const int j = slot - (s ? 2566 : 0);
        if (j < 2566) {
            const WSet A = s ? a1 : a0;
            wprep_core(A, W1f + (size_t)s * 491520, W2af + (size_t)s * 65536,
                       W2bf + (size_t)s * 98304, B1p + s * 1280, B2bp + s * 128,
                       j * 256 + t);
        }
        return;
    }
    xprep_core(x, xT, x1T, xt, bx, by, bz, t);
}

// ---------------- fused MLP v6 + cvt_pk hs-pack (verbatim R11, 105.3 us verified) ----------------
__global__ __launch_bounds__(512, 4) void fused_mlp(
    const short* __restrict__ W1f_, const float* __restrict__ B1p_,
    const short* __restrict__ W2af_, const float* __restrict__ fb2_0, const float* __restrict__ fb2_1,
    const short* __restrict__ W2bf_, const float* __restrict__ B2bp_,
    const short* __restrict__ xT, const short* __restrict__ x1T,
    float* __restrict__ feat0, float* __restrict__ feat1,
    short* __restrict__ Eg0, short* __restrict__ Eg1,
    float* __restrict__ pu0, float* __restrict__ pu1)
{
    __shared__ short xs[12 * 2048];   // 48 KB
    __shared__ short hs[8 * 2048];    // 32 KB (256 k-rows x 64 n, B-fragment order)
    const int tid = threadIdx.x;
    const int wid = tid >> 6, lane = tid & 63;   // wid 0..7
    const int l15 = lane & 15, q = lane >> 4;
    const int bx = blockIdx.x, b = blockIdx.y;
    const int sc = bx >= 64;
    const int tile = sc ? bx - 64 : bx;
    const int N = sc ? 1024 : 4096;
    const int n0 = tile * 64;
    const short* XT = sc ? x1T : xT;
    const short* W1f = W1f_ + (size_t)sc * 491520;
    const float* B1p = B1p_ + sc * 1280;
    const short* W2af = W2af_ + (size_t)sc * 65536;
    const short* W2bf = W2bf_ + (size_t)sc * 98304;
    const float* fb2 = sc ? fb2_1 : fb2_0;
    const float* B2bp = B2bp_ + sc * 128;
    float* feat = (sc ? feat1 : feat0) + (long)b * 128 * N;
    short* Eg = (sc ? Eg1 : Eg0) + (long)b * 65 * N;
    float* pu = sc ? pu1 : pu0;
    const int npart = sc ? 16 : 64;

    // stage x tile [64 n x 384 k] into fragment-order LDS (512 threads)
    {
        const int n = tid >> 3;          // 0..63
        const int c0 = (tid & 7) * 6;    // 8 threads cover 48 c-groups
        const short* src = XT + ((long)b * N + n0 + n) * 384 + c0 * 8;
        const int jj = n >> 4, nl = n & 15;
        #pragma unroll
        for (int i = 0; i < 6; i++) {
            int c = c0 + i;
            int kc = c >> 2, qq = c & 3;
            *(short8*)(xs + kc * 2048 + jj * 512 + ((qq << 4) | nl) * 8) =
                *(const short8*)(src + i * 8);
        }
    }
    __syncthreads();

    floatx4 acc2[2][4];   // [0] = feat group wid, [1] = E group wid (wid<5)
    #pragma unroll
    for (int i = 0; i < 2; i++)
        #pragma unroll
        for (int j = 0; j < 4; j++) acc2[i][j] = floatx4{0.f, 0.f, 0.f, 0.f};

    auto phase2 = [&](int pc) {
        if (pc < 2) {
            const short* WA = W2af + (size_t)pc * 32768;
            short8 hb[2][4], wa[2];
            #pragma unroll
            for (int j = 0; j < 4; j++) hb[0][j] = *(short8*)(hs + j * 512 + lane * 8);
            wa[0] = *(const short8*)(WA + wid * 512 + lane * 8);
            #pragma unroll
            for (int kc2 = 0; kc2 < 8; kc2++) {
                short8 bfr[4];
                #pragma unroll
                for (int j = 0; j < 4; j++) bfr[j] = hb[kc2 & 1][j];
                short8 aF = wa[kc2 & 1];
                if (kc2 + 1 < 8) {
                    #pragma unroll
                    for (int j = 0; j < 4; j++)
                        hb[(kc2 + 1) & 1][j] = *(short8*)(hs + (kc2 + 1) * 2048 + j * 512 + lane * 8);
                    wa[(kc2 + 1) & 1] = *(const short8*)(WA + ((kc2 + 1) * 8 + wid) * 512 + lane * 8);
                }
                #pragma unroll
                for (int j = 0; j < 4; j++)
                    acc2[0][j] = __builtin_amdgcn_mfma_f32_16x16x32_bf16(aF, bfr[j], acc2[0][j], 0, 0, 0);
            }
        } else {
            if (wid >= 5) return;   // wave-uniform: E rows only on waves 0..4
            const short* WB = W2bf + (size_t)(pc - 2) * 32768;
            short8 hb[2][4], we[2];
            #pragma unroll
            for (int j = 0; j < 4; j++) hb[0][j] = *(short8*)(hs + j * 512 + lane * 8);
            we[0] = *(const short8*)(WB + wid * 512 + lane * 8);
            #pragma unroll
            for (int kc2 = 0; kc2 < 8; kc2++) {
                short8 bfr[4];
                #pragma unroll
                for (int j = 0; j < 4; j++) bfr[j] = hb[kc2 & 1][j];
                short8 aE = we[kc2 & 1];
                if (kc2 + 1 < 8) {
                    #pragma unroll
                    for (int j = 0; j < 4; j++)
                        hb[(kc2 + 1) & 1][j] = *(short8*)(hs + (kc2 + 1) * 2048 + j * 512 + lane * 8);
                    we[(kc2 + 1) & 1] = *(const short8*)(WB + ((kc2 + 1) * 8 + wid) * 512 + lane * 8);
                }
                #pragma unroll
                for (int j = 0; j < 4; j++)
                    acc2[1][j] = __builtin_amdgcn_mfma_f32_16x16x32_bf16(aE, bfr[j], acc2[1][j], 0, 0, 0);
            }
        }
    };

    for (int c = 0; c < 5; c++) {
        if (c > 0) phase2(c - 1);   // reads hs chunk c-1 (published at end of prev iter)
        // phase1: h rows c*256 + wid*32 .. +31; 2-deep global A prefetch
        floatx4 acc1[2][4];
        #pragma unroll
        for (int i = 0; i < 2; i++)
            #pragma unroll
            for (int j = 0; j < 4; j++) acc1[i][j] = floatx4{0.f, 0.f, 0.f, 0.f};
        const short* Wb = W1f + (long)c * 98304;
        short8 abuf[2][2];
        #pragma unroll
        for (int i = 0; i < 2; i++) {
            abuf[0][i] = *(const short8*)(Wb + (wid * 2 + i) * 512 + lane * 8);
            abuf[1][i] = *(const short8*)(Wb + (16 + wid * 2 + i) * 512 + lane * 8);
        }
        #pragma unroll
        for (int kc = 0; kc < 12; kc++) {
            short8 ac[2], bc[4];
            #pragma unroll
            for (int i = 0; i < 2; i++) ac[i] = abuf[kc & 1][i];
            #pragma unroll
            for (int j = 0; j < 4; j++) bc[j] = *(short8*)(xs + kc * 2048 + j * 512 + lane * 8);
            if (kc + 2 < 12) {
                #pragma unroll
                for (int i = 0; i < 2; i++)
                    abuf[kc & 1][i] = *(const short8*)(Wb + ((kc + 2) * 16 + wid * 2 + i) * 512 + lane * 8);
            }
            #pragma unroll
            for (int i = 0; i < 2; i++)
                #pragma unroll
                for (int j = 0; j < 4; j++)
                    acc1[i][j] = __builtin_amdgcn_mfma_f32_16x16x32_bf16(ac[i], bc[j], acc1[i][j], 0, 0, 0);
        }
        __syncthreads();   // hs readers (phase2 of chunk c-1) done
        // h-chunk -> hs (bias + relu + bf16 via cvt_pk), phase-2 B-fragment order
        #pragma unroll
        for (int i = 0; i < 2; i++) {
            const int qf = i * 2 + (q >> 1);
            const int e0 = 4 * (q & 1);
            const int mrow = c * 256 + wid * 32 + i * 16 + q * 4;
            float bw[4];
            #pragma unroll
            for (int rr = 0; rr < 4; rr++) bw[rr] = B1p[mrow + rr];
            #pragma unroll
            for (int j = 0; j < 4; j++) {
                float r0 = fmaxf(acc1[i][j][0] + bw[0], 0.f);
                float r1 = fmaxf(acc1[i][j][1] + bw[1], 0.f);
                float r2 = fmaxf(acc1[i][j][2] + bw[2], 0.f);
                float r3 = fmaxf(acc1[i][j][3] + bw[3], 0.f);
                unsigned lo = cvtpk2(r0, r1), hi = cvtpk2(r2, r3);
                unsigned long long pk = ((unsigned long long)hi << 32) | lo;
                *(unsigned long long*)(hs + wid * 2048 + j * 512 + ((qf << 4) | l15) * 8 + e0) = pk;
            }
        }
        __syncthreads();   // hs visible
    }
    phase2(4);

    // epilogue: feat (every wave owns rows wid*16 .. +15)
    {
        const int row0 = wid * 16 + q * 4;
        #pragma unroll
        for (int rr = 0; rr < 4; rr++) {
            float bv = fb2[row0 + rr];
            #pragma unroll
            for (int j = 0; j < 4; j++)
                feat[(long)(row0 + rr) * N + n0 + 16 * j + l15] = acc2[0][j][rr] + bv;
        }
    }
    __syncthreads();               // all phase2(4) hs reads done; reuse hs
    float* puld = (float*)hs;
    if (wid < 4) {
        // E rows wid*16 .. +15
        #pragma unroll
        for (int rr = 0; rr < 4; rr++) {
            int row = wid * 16 + q * 4 + rr;
            float bv = B2bp[row];
            float s = 0.f;
            #pragma unroll
            for (int j = 0; j < 4; j++) {
                float e = expf(acc2[1][j][rr] + bv);
                Eg[(long)row * N + n0 + 16 * j + l15] = f2bf(e);
                s += e;
            }
            s += __shfl_xor(s, 1); s += __shfl_xor(s, 2);
            s += __shfl_xor(s, 4); s += __shfl_xor(s, 8);
            if (l15 == 0) puld[row] = s;
        }
    } else if (wid == 4) {
        // dustbin row 64 only
        #pragma unroll
        for (int rr = 0; rr < 4; rr++) {
            int row = 64 + q * 4 + rr;
            bool valid = (row == 64);
            float bv = B2bp[64];
            float s = 0.f;
            #pragma unroll
            for (int j = 0; j < 4; j++) {
                float e = expf(acc2[1][j][rr] + bv);
                if (valid) {
                    Eg[(long)64 * N + n0 + 16 * j + l15] = f2bf(e);
                    s += e;
                }
            }
            s += __shfl_xor(s, 1); s += __shfl_xor(s, 2);
            s += __shfl_xor(s, 4); s += __shfl_xor(s, 8);
            if (valid && l15 == 0) puld[64] = s;
        }
    }
    __syncthreads();
    if (tid < 65)
        pu[((long)b * npart + tile) * 65 + tid] = puld[tid];
}

// ---------------- sk_step: 128-col chunks (640 blocks) ----------------
__global__ __launch_bounds__(256) void sk_step(
    const short* __restrict__ Eg0, const short* __restrict__ Eg1,
    const float* __restrict__ pin0, const float* __restrict__ pin1,
    float* __restrict__ pout0, float* __restrict__ pout1, int nin0, int nin1)
{
    __shared__ short Es[65 * 136];    // 17680 B
    __shared__ float evs[128];
    __shared__ float eus[65];
    const int t = threadIdx.x;
    const int bx = blockIdx.x, b = blockIdx.y;
    const int sc = bx >= 32;
    const int chunk = sc ? bx - 32 : bx;
    const int N = sc ? 1024 : 4096;
    const float invN = sc ? (1.0f / 1024.0f) : (1.0f / 4096.0f);
    const int n0 = chunk * 128;
    const short* Eb = (sc ? Eg1 : Eg0) + (long)b * 65 * N;
    const float* pin = sc ? pin1 : pin0;
    const int nin = sc ? nin1 : nin0;
    float* pout = sc ? pout1 : pout0;
    const int nout = sc ? 8 : 32;
    if (t < 65) {
        float s = 0.f;
        for (int ch = 0; ch < nin; ch++) s += pin[((long)b * nin + ch) * 65 + t];
        eus[t] = (1.0f / 65.0f) / s;
    }
    for (int it = t; it < 1040; it += 256) {
        int k = it >> 4, n8 = it & 15;
        *(short8*)(Es + k * 136 + n8 * 8) = *(const short8*)(Eb + (long)k * N + n0 + n8 * 8);
    }
    __syncthreads();
    if (t < 128) {
        float sv = 0.f;
        #pragma unroll 4
        for (int k = 0; k < 65; k++) sv += bf2f(Es[k * 136 + t]) * eus[k];
        evs[t] = invN / sv;
    }
    __syncthreads();
    const int wid = t >> 6, lane = t & 63;
    for (int k = wid; k < 65; k += 4) {
        const short* er = Es + k * 136 + lane * 2;
        float2 v2 = *(const float2*)&evs[lane * 2];
        float s = bf2f(er[0]) * v2.x + bf2f(er[1]) * v2.y;
        #pragma unroll
        for (int off = 32; off >= 1; off >>= 1) s += __shfl_xor(s, off);
        if (lane == 0) pout[((long)b * nout + chunk) * 65 + k] = s;
    }
}

// ---------------- sk_desc: 128-col chunks; eu; final v-step; desc partials via MFMA ----------------
__global__ __launch_bounds__(256) void sk_desc(
    const short* __restrict__ Eg0, const short* __restrict__ Eg1,
    const float* __restrict__ pin0, const float* __restrict__ pin1,
    const float* __restrict__ feat0, const float* __restrict__ feat1,
    float* __restrict__ part0, float* __restrict__ part1, int nin0, int nin1)
{
    __shared__ short Es[65 * 136];
    __shared__ float eus[65];
    __shared__ float evs[128];
    const int t = threadIdx.x;
    const int bx = blockIdx.x, b = blockIdx.y;
    const int sc = bx >= 32;
    const int chunk = sc ? bx - 32 : bx;
    const int N = sc ? 1024 : 4096;
    const float invN = sc ? (1.0f / 1024.0f) : (1.0f / 4096.0f);
    const int nch = sc ? 8 : 32;
    const int n0 = chunk * 128;
    const short* Eb = (sc ? Eg1 : Eg0) + (long)b * 65 * N;
    const float* pin = sc ? pin1 : pin0;
    const int nin = sc ? nin1 : nin0;
    const float* fb = (sc ? feat1 : feat0) + (long)b * 128 * N;
    float* part = sc ? part1 : part0;
    if (t < 65) {
        float s = 0.f;
        for (int ch = 0; ch < nin; ch++) s += pin[((long)b * nin + ch) * 65 + t];
        eus[t] = (1.0f / 65.0f) / s;
    }
    for (int it = t; it < 1040; it += 256) {
        int k = it >> 4, n8 = it & 15;
        *(short8*)(Es + k * 136 + n8 * 8) = *(const short8*)(Eb + (long)k * N + n0 + n8 * 8);
    }
    __syncthreads();
    if (t < 128) {
        float sv = 0.f;
        #pragma unroll 4
        for (int k = 0; k < 65; k++) sv += bf2f(Es[k * 136 + t]) * eus[k];
        evs[t] = invN / sv;
    }
    __syncthreads();
    const int wid = t >> 6, lane = t & 63;
    const int l15 = lane & 15, q = lane >> 4;
    float* pb = part + ((long)b * nch + chunk) * 8256;
    // P row-sum partials: eu[k] * sum_n E[k,n]*ev[n]
    for (int k = wid; k < 64; k += 4) {
        const short* er = Es + k * 136 + lane * 2;
        float2 v2 = *(const float2*)&evs[lane * 2];
        float s = bf2f(er[0]) * v2.x + bf2f(er[1]) * v2.y;
        #pragma unroll
        for (int off = 32; off >= 1; off >>= 1) s += __shfl_xor(s, off);
        if (lane == 0) pb[8192 + k] = s * eus[k];
    }
    // MFMA einsum: wave wid owns c rows wid*32..+31 (2 m-tiles), 64 k-cols (4 n-tiles)
    floatx4 acc[2][4];
    #pragma unroll
    for (int mt = 0; mt < 2; mt++)
        #pragma unroll
        for (int nt = 0; nt < 4; nt++) acc[mt][nt] = floatx4{0.f, 0.f, 0.f, 0.f};
    #pragma unroll
    for (int ks = 0; ks < 4; ks++) {
        float4 ev0 = *(const float4*)&evs[ks * 32 + q * 8];
        float4 ev1 = *(const float4*)&evs[ks * 32 + q * 8 + 4];
        float evq[8] = {ev0.x, ev0.y, ev0.z, ev0.w, ev1.x, ev1.y, ev1.z, ev1.w};
        short8 ah[2], al[2];
        #pragma unroll
        for (int mt = 0; mt < 2; mt++) {
            const float* fp = fb + (long)(wid * 32 + mt * 16 + l15) * N + n0 + ks * 32 + q * 8;
            float4 v0 = *(const float4*)fp;
            float4 v1 = *(const float4*)(fp + 4);
            float va[8] = {v0.x, v0.y, v0.z, v0.w, v1.x, v1.y, v1.z, v1.w};
            short hh[8], ll[8];
            #pragma unroll
            for (int e = 0; e < 8; e++) {
                float sv2 = va[e] * evq[e];
                short h = f2bf(sv2);
                hh[e] = h;
                ll[e] = f2bf(sv2 - bf2f(h));
            }
            ah[mt] = *(short8*)hh;
            al[mt] = *(short8*)ll;
        }
        #pragma unroll
        for (int nt = 0; nt < 4; nt++) {
            short8 bfr = *(short8*)(Es + (nt * 16 + l15) * 136 + ks * 32 + q * 8);
            #pragma unroll
            for (int mt = 0; mt < 2; mt++) {
                acc[mt][nt] = __builtin_amdgcn_mfma_f32_16x16x32_bf16(al[mt], bfr, acc[mt][nt], 0, 0, 0);
                acc[mt][nt] = __builtin_amdgcn_mfma_f32_16x16x32_bf16(ah[mt], bfr, acc[mt][nt], 0, 0, 0);
            }
        }
    }
    #pragma unroll
    for (int nt = 0; nt < 4; nt++) {
        float euk = eus[nt * 16 + l15];
        #pragma unroll
        for (int mt = 0; mt < 2; mt++)
            #pragma unroll
            for (int rr = 0; rr < 4; rr++)
                pb[(wid * 32 + mt * 16 + q * 4 + rr) * 64 + nt * 16 + l15] = acc[mt][nt][rr] * euk;
    }
}

// ---------------- dred1 core ----------------
__device__ inline void dred1_core(
    const float* __restrict__ part0, const float* __restrict__ part1,
    float* __restrict__ asum, float* __restrict__ colp2,
    float (*rsv)[64], float* sqs, int j, int b, int t)
{
    // row-sum reciprocals (wave0: scale0, wave1: scale1)
    if (t < 128) {
        int s = t >> 6, k = t & 63;
        int nch = s ? 8 : 32;
        const float* pr = (s ? part1 : part0) + (long)b * nch * 8256 + 8192 + k;
        float rs = 0.f;
        for (int ch = 0; ch < nch; ch++) rs += pr[ch * 8256];
        rsv[s][k] = 1.0f / (rs + 1e-8f);
    }
    __syncthreads();
    const int kk = t & 63;
    #pragma unroll
    for (int s = 0; s < 2; s++) {
        const int nch = s ? 8 : 32;
        const float* pb = (s ? part1 : part0) + (long)b * nch * 8256 + j * 1024;
        float a[4];
        #pragma unroll
        for (int i = 0; i < 4; i++) a[i] = 0.f;
        for (int ch = 0; ch < nch; ch++) {
            const float* p = pb + (long)ch * 8256;
            #pragma unroll
            for (int i = 0; i < 4; i++) a[i] += p[t + 256 * i];
        }
        float rk = rsv[s][kk];
        #pragma unroll
        for (int i = 0; i < 4; i++) a[i] *= rk;
        float* as = asum + ((long)(b * 2 + s)) * 8192 + j * 1024;
        #pragma unroll
        for (int i = 0; i < 4; i++) as[t + 256 * i] = a[i];
        float sq = a[0] * a[0] + a[1] * a[1] + a[2] * a[2] + a[3] * a[3];
        sqs[t] = sq;
        __syncthreads();
        if (t < 64)
            colp2[(((long)(b * 2 + s)) * 8 + j) * 64 + t] =
                sqs[t] + sqs[t + 64] + sqs[t + 128] + sqs[t + 192];
        __syncthreads();
    }
}

// ---------------- standalone dred1/dred2 (CB<16 fallback, R11-verified) ----------------
__global__ __launch_bounds__(256) void dred1(
    const float* __restrict__ part0, const float* __restrict__ part1,
    float* __restrict__ asum, float* __restrict__ colp2)
{
    __shared__ float rsv[2][64];
    __shared__ float sqs[256];
    dred1_core(part0, part1, asum, colp2, rsv, sqs, blockIdx.x, blockIdx.y, threadIdx.x);
}

__global__ __launch_bounds__(1024) void dred2(
    const float* __restrict__ asum, const float* __restrict__ colp2,
    float* __restrict__ out, int b0)
{
    __shared__ float inv0[64], inv1[64];
    __shared__ float red[16];
    const int b = blockIdx.x;
    const int t = threadIdx.x;
    const int wv = t >> 6, l = t & 63;
    if (t < 128) {
        int s = t >> 6, k = t & 63;
        float sq = 0.f;
        #pragma unroll
        for (int j = 0; j < 8; j++) sq += colp2[(((long)(b * 2 + s)) * 8 + j) * 64 + k];
        float iv = 1.0f / fmaxf(sqrtf(sq), 1e-12f);
        (s ? inv1 : inv0)[k] = iv;
    }
    __syncthreads();
    const int kk = t & 63;
    float i0 = inv0[kk], i1 = inv1[kk];
    const float* a0 = asum + ((long)(b * 2)) * 8192;
    const float* a1 = asum + ((long)(b * 2 + 1)) * 8192;
    float g[8];
    float ssum = 0.f;
    #pragma unroll
    for (int i = 0; i < 8; i++) {
        int e = t + 1024 * i;
        float v = (a0[e] * i0 + a1[e] * i1) * 0.5f;
        g[i] = v; ssum += v * v;
    }
    #pragma unroll
    for (int off = 32; off >= 1; off >>= 1) ssum += __shfl_xor(ssum, off);
    if (l == 0) red[wv] = ssum;
    __syncthreads();
    float tot = 0.f;
    #pragma unroll
    for (int w2 = 0; w2 < 16; w2++) tot += red[w2];
    float inv = 1.0f / fmaxf(sqrtf(tot), 1e-12f);
    float* o = out + (long)(b0 + b) * 8192;
    #pragma unroll
    for (int i = 0; i < 8; i++) o[t + 1024 * i] = g[i] * inv;
}

// ---------------- dred_fan (CB==16): dred1 + device fan-in; last block per batch does dred2 ----------------
// rocPRIM-style decoupled fan-in: writers threadfence + atomicAdd; rank-7 block re-fences
// then performs dred2's work for its batch with 256 threads. No grid barrier; deadlock-free.
__global__ __launch_bounds__(256) void dred_fan(
    const float* __restrict__ part0, const float* __restrict__ part1,
    float* __restrict__ asum, float* __restrict__ colp2,
    float* __restrict__ out, int b0, unsigned* __restrict__ ctr)
{
    __shared__ float rsv[2][64];
    __shared__ float sqs[256];
    const int j = blockIdx.x, b = blockIdx.y;
    const int t = threadIdx.x;
    dred1_core(part0, part1, asum, colp2, rsv, sqs, j, b, t);

    __threadfence();
    __shared__ unsigned rank;
    if (t == 0) rank = atomicAdd(&ctr[b], 1u);
    __syncthreads();
    if (rank != 7) return;
    __threadfence();

    // ---- dred2 for batch b, 256 threads ----
    __shared__ float inv0[64], inv1[64];
    __shared__ float red[4];
    if (t < 128) {
        int s = t >> 6, k = t & 63;
        float sq = 0.f;
        #pragma unroll
        for (int jj = 0; jj < 8; jj++) sq += colp2[(((long)(b * 2 + s)) * 8 + jj) * 64 + k];
        float iv = 1.0f / fmaxf(sqrtf(sq), 1e-12f);
        (s ? inv1 : inv0)[k] = iv;
    }
    __syncthreads();
    const int kk = t & 63;
    const int wv = t >> 6, l = t & 63;
    float i0 = inv0[kk], i1 = inv1[kk];
    const float* a0 = asum + ((long)(b * 2)) * 8192;
    const float* a1 = asum + ((long)(b * 2 + 1)) * 8192;
    float g[32];
    float ssum = 0.f;
    #pragma unroll
    for (int i = 0; i < 32; i++) {
        int e = t + 256 * i;          // e mod 64 == t mod 64
        float v = (a0[e] * i0 + a1[e] * i1) * 0.5f;
        g[i] = v; ssum += v * v;
    }
    #pragma unroll
    for (int off = 32; off >= 1; off >>= 1) ssum += __shfl_xor(ssum, off);
    if (l == 0) red[wv] = ssum;
    __syncthreads();
    float tot = red[0] + red[1] + red[2] + red[3];
    float inv = 1.0f / fmaxf(sqrtf(tot), 1e-12f);
    float* o = out + (long)(b0 + b) * 8192;
    #pragma unroll
    for (int i = 0; i < 32; i++) o[t + 256 * i] = g[i] * inv;
}

extern "C" void kernel_launch(void* const* d_in, const int* in_sizes, int n_in,
                              void* d_out, int out_size, void* d_ws, size_t ws_size,
                              hipStream_t stream)
{
    (void)in_sizes; (void)n_in; (void)out_size;
    const float* x = (const float*)d_in[0];
    WSet ws2[2];
    const float* fb2p[2];
    for (int s = 0; s < 2; s++) {
        int o = 1 + s * 12;
        ws2[s].fw1 = (const float*)d_in[o + 0];  ws2[s].fb1 = (const float*)d_in[o + 1];
        ws2[s].fw2 = (const float*)d_in[o + 2];  fb2p[s]    = (const float*)d_in[o + 3];
        ws2[s].sw1 = (const float*)d_in[o + 4];  ws2[s].sb1 = (const float*)d_in[o + 5];
        ws2[s].sw2 = (const float*)d_in[o + 6];  ws2[s].sb2 = (const float*)d_in[o + 7];
        ws2[s].dw1 = (const float*)d_in[o + 8];  ws2[s].db1 = (const float*)d_in[o + 9];
        ws2[s].dw2 = (const float*)d_in[o + 10]; ws2[s].db2 = (const float*)d_in[o + 11];
    }

    // part0/part1 alias xT/x1T (dead after fused_mlp reads them; stream-ordered safe).
    const size_t fixed = ((size_t)2*491520*2 + 2*65536*2 + 2*98304*2
                        + 2*1280*4 + 2*128*4) + (1 << 16);
    const size_t perb = (size_t)4096*384*2 + (size_t)1024*384*2
                      + (size_t)128*4096*4 + (size_t)128*1024*4
                      + (size_t)65*4096*2 + (size_t)65*1024*2
                      + (size_t)(64+16)*65*4 + (size_t)(32+8)*65*4
                      + (size_t)2*8192*4 + (size_t)2*8*64*4 + 8192;
    int CB = 4;
    const int cand[3] = {16, 8, 4};
    for (int ci = 0; ci < 3; ci++)
        if (fixed + (size_t)cand[ci] * perb <= ws_size) { CB = cand[ci]; break; }

    char* p = (char*)d_ws;
    auto alloc = [&](size_t bytes) -> char* {
        char* r = p; p += (bytes + 255) & ~(size_t)255; return r;
    };
    short* W1f   = (short*)alloc((size_t)2 * 491520 * 2);
    short* W2af  = (short*)alloc((size_t)2 * 65536 * 2);
    short* W2bf  = (short*)alloc((size_t)2 * 98304 * 2);
    float* B1p   = (float*)alloc((size_t)2 * 1280 * 4);
    float* B2bp  = (float*)alloc((size_t)2 * 128 * 4);
    short* xT    = (short*)alloc((size_t)CB * 4096 * 384 * 2);
    short* x1T   = (short*)alloc((size_t)CB * 1024 * 384 * 2);
    float* feat0 = (float*)alloc((size_t)CB * 128 * 4096 * 4);
    float* feat1 = (float*)alloc((size_t)CB * 128 * 1024 * 4);
    short* Eg0   = (short*)alloc((size_t)CB * 65 * 4096 * 2);
    short* Eg1   = (short*)alloc((size_t)CB * 65 * 1024 * 2);
    float* puA0  = (float*)alloc((size_t)CB * 64 * 65 * 4);
    float* puA1  = (float*)alloc((size_t)CB * 16 * 65 * 4);
    float* puB0  = (float*)alloc((size_t)CB * 32 * 65 * 4);
    float* puB1  = (float*)alloc((size_t)CB * 8 * 65 * 4);
    float* asum  = (float*)alloc((size_t)CB * 2 * 8192 * 4);
    float* colp2 = (float*)alloc((size_t)CB * 2 * 8 * 64 * 4);
    unsigned* ctr = (unsigned*)alloc(64);
    // aliases (xT: CB*3.15 MB >= CB*32*8256*4 = CB*1.06 MB; x1T: CB*0.79 >= CB*0.26)
    float* part0 = (float*)xT;
    float* part1 = (float*)x1T;

    if (CB == 16) {
        // 6-dispatch path: prep2(wprep+xprep+ctr-zero) -> fused -> sk1 -> sk2 -> skd -> dred_fan
        prep2<<<dim3(86, 6, 16), 256, 0, stream>>>(ws2[0], ws2[1],
            W1f, W2af, W2bf, B1p, B2bp, x, xT, x1T, ctr);
        fused_mlp<<<dim3(80, 16), 512, 0, stream>>>(
            W1f, B1p, W2af, fb2p[0], fb2p[1], W2bf, B2bp,
            xT, x1T, feat0, feat1, Eg0, Eg1, puA0, puA1);
        sk_step<<<dim3(40, 16), 256, 0, stream>>>(Eg0, Eg1, puA0, puA1, puB0, puB1, 64, 16);
        sk_step<<<dim3(40, 16), 256, 0, stream>>>(Eg0, Eg1, puB0, puB1, puA0, puA1, 32, 8);
        sk_desc<<<dim3(40, 16), 256, 0, stream>>>(Eg0, Eg1, puA0, puA1,
                                                  feat0, feat1, part0, part1, 32, 8);
        dred_fan<<<dim3(8, 16), 256, 0, stream>>>(part0, part1, asum, colp2,
                                                  (float*)d_out, 0, ctr);
    } else {
        wprep<<<dim3(2566, 2), 256, 0, stream>>>(ws2[0], ws2[1], W1f, W2af, W2bf, B1p, B2bp);
        for (int b0 = 0; b0 < 16; b0 += CB) {
            xprep<<<dim3(32, 6, CB), 256, 0, stream>>>(x + (size_t)b0 * 384 * 4096, xT, x1T);
            fused_mlp<<<dim3(80, CB), 512, 0, stream>>>(
                W1f, B1p, W2af, fb2p[0], fb2p[1], W2bf, B2bp,
                xT, x1T, feat0, feat1, Eg0, Eg1, puA0, puA1);
            sk_step<<<dim3(40, CB), 256, 0, stream>>>(Eg0, Eg1, puA0, puA1, puB0, puB1, 64, 16);
            sk_step<<<dim3(40, CB), 256, 0, stream>>>(Eg0, Eg1, puB0, puB1, puA0, puA1, 32, 8);
            sk_desc<<<dim3(40, CB), 256, 0, stream>>>(Eg0, Eg1, puA0, puA1,
                                                      feat0, feat1, part0, part1, 32, 8);
            dred1<<<dim3(8, CB), 256, 0, stream>>>(part0, part1, asum, colp2);
            dred2<<<dim3(CB), 1024, 0, stream>>>(asum, colp2, (float*)d_out, b0);
        }
    }
}

// Round 13
// 385.161 us; speedup vs baseline: 1.0410x; 1.0410x over previous
//
#include <hip/hip_runtime.h>
#include <math.h>

typedef __attribute__((ext_vector_type(8))) short short8;
typedef __attribute__((ext_vector_type(4))) float floatx4;

__device__ inline float bf2f(short s) {
    union { unsigned u; float f; } x; x.u = ((unsigned)(unsigned short)s) << 16; return x.f;
}
__device__ inline short f2bf(float f) {
    union { float f; unsigned u; } x; x.f = f;
    unsigned r = x.u + 0x7fff + ((x.u >> 16) & 1);
    return (short)(r >> 16);
}
// pack 2 f32 -> 2 bf16 (RNE) in one instruction; lo = src0, hi = src1
__device__ inline unsigned cvtpk2(float a, float b) {
    unsigned r;
    asm("v_cvt_pk_bf16_f32 %0, %1, %2" : "=v"(r) : "v"(a), "v"(b));
    return r;
}

struct WSet {
    const float *fw1, *fb1, *fw2, *sw1, *sb1, *sw2, *sb2, *dw1, *db1, *dw2, *db2;
};

// ---------------- weight prep ----------------
// W1f: [c 0..4][kc 0..11][g 0..15][lane][8]; m=c*256+g*16+(l&15) (0-pad >=1152), k=kc*32+(l>>4)*8+e
// W2af: [ka 0..15][g 0..7][lane][8] from fw2 [128x512]
// W2bf: [kb 0..23][g 0..7][lane][8]; r=g*16+(l&15): sw2 (r<64,krel<512) / dw2 (r==64,512<=krel<640) / 0
__global__ __launch_bounds__(256) void wprep(WSet a0, WSet a1,
    short* __restrict__ W1f, short* __restrict__ W2af, short* __restrict__ W2bf,
    float* __restrict__ B1p, float* __restrict__ B2bp)
{
    const int s = blockIdx.y;
    const WSet A = s ? a1 : a0;
    W1f  += (size_t)s * 491520;
    W2af += (size_t)s * 65536;
    W2bf += (size_t)s * 98304;
    B1p  += s * 1280;
    B2bp += s * 128;
    int id = blockIdx.x * 256 + threadIdx.x;
    if (id < 491520) {
        int e = id & 7, l = (id >> 3) & 63, g = (id >> 9) & 15, rest = id >> 13;
        int kc = rest % 12, c = rest / 12;
        int m = c * 256 + g * 16 + (l & 15);
        int k = kc * 32 + (l >> 4) * 8 + e;
        float v = 0.f;
        if (m < 512) v = A.fw1[m * 384 + k];
        else if (m < 1024) v = A.sw1[(m - 512) * 384 + k];
        else if (m < 1152) v = A.dw1[(m - 1024) * 384 + k];
        W1f[id] = f2bf(v);
        return;
    }
    id -= 491520;
    if (id < 65536) {
        int e = id & 7, l = (id >> 3) & 63, g = (id >> 9) & 7, ka = id >> 12;
        int r = g * 16 + (l & 15), k = ka * 32 + (l >> 4) * 8 + e;
        W2af[id] = f2bf(A.fw2[r * 512 + k]);
        return;
    }
    id -= 65536;
    if (id < 98304) {
        int e = id & 7, l = (id >> 3) & 63, g = (id >> 9) & 7, kb = id >> 12;
        int r = g * 16 + (l & 15), krel = kb * 32 + (l >> 4) * 8 + e;
        float v = 0.f;
        if (r < 64 && krel < 512) v = A.sw2[r * 512 + krel];
        else if (r == 64 && krel >= 512 && krel < 640) v = A.dw2[krel - 512];
        W2bf[id] = f2bf(v);
        return;
    }
    id -= 98304;
    if (id < 1280) {
        float v = 0.f;
        if (id < 512) v = A.fb1[id];
        else if (id < 1024) v = A.sb1[id - 512];
        else if (id < 1152) v = A.db1[id - 1024];
        B1p[id] = v;
        return;
    }
    id -= 1280;
    if (id < 128) B2bp[id] = id < 64 ? A.sb2[id] : id == 64 ? A.db2[0] : 0.f;
}

// ---------------- xprep (float4 x loads, cvt_pk packing) ----------------
__global__ __launch_bounds__(256) void xprep(const float* __restrict__ x,
                                             short* __restrict__ xT, short* __restrict__ x1T)
{
    __shared__ float xt[64 * 129];
    const int ip = blockIdx.x;
    const int cg = blockIdx.y;
    const int b  = blockIdx.z;
    const int t  = threadIdx.x;
    #pragma unroll
    for (int u = 0; u < 8; u++) {
        int idx = t + 256 * u;             // 0..2047 float4 slots
        int c = idx >> 5, spq = idx & 31;  // sp = spq*4
        float4 v = *(const float4*)&x[(((long)b * 384 + cg * 64 + c) * 64 + ip * 2 + (spq >> 4)) * 64 + (spq & 15) * 4];
        float* d = &xt[c * 129 + spq * 4];
        d[0] = v.x; d[1] = v.y; d[2] = v.z; d[3] = v.w;
    }
    __syncthreads();
    {
        int sp = t >> 1, ch = t & 1;
        unsigned tmp[16];
        #pragma unroll
        for (int cc = 0; cc < 16; cc++)
            tmp[cc] = cvtpk2(xt[(ch * 32 + 2 * cc) * 129 + sp], xt[(ch * 32 + 2 * cc + 1) * 129 + sp]);
        short* dst = xT + ((long)b * 4096 + ip * 128 + sp) * 384 + cg * 64 + ch * 32;
        #pragma unroll
        for (int v = 0; v < 4; v++) *(short8*)(dst + v * 8) = *(short8*)(tmp + v * 4);
    }
    {
        int j1 = t >> 3, c8 = t & 7;
        unsigned tmp[4];
        #pragma unroll
        for (int e = 0; e < 4; e++) {
            int c = c8 * 8 + 2 * e;
            float v0 = 0.25f * (xt[c * 129 + j1 * 2]      + xt[c * 129 + j1 * 2 + 1] +
                                xt[c * 129 + 64 + j1 * 2] + xt[c * 129 + 64 + j1 * 2 + 1]);
            float v1 = 0.25f * (xt[(c + 1) * 129 + j1 * 2]      + xt[(c + 1) * 129 + j1 * 2 + 1] +
                                xt[(c + 1) * 129 + 64 + j1 * 2] + xt[(c + 1) * 129 + 64 + j1 * 2 + 1]);
            tmp[e] = cvtpk2(v0, v1);
        }
        *(short8*)(x1T + ((long)b * 1024 + ip * 32 + j1) * 384 + cg * 64 + c8 * 8) = *(short8*)tmp;
    }
}

// ---------------- fused MLP v6 + cvt_pk hs-pack (verbatim R11, 105.3 us verified) ----------------
// n=64 tile, 512 threads / 8 waves of 32 m-rows each. 2 blocks/CU (80 KB LDS).
// Do not re-split phase1 n (v7 L2 regression); do not merge dispatches (R7/R12 regressions).
__global__ __launch_bounds__(512, 4) void fused_mlp(
    const short* __restrict__ W1f_, const float* __restrict__ B1p_,
    const short* __restrict__ W2af_, const float* __restrict__ fb2_0, const float* __restrict__ fb2_1,
    const short* __restrict__ W2bf_, const float* __restrict__ B2bp_,
    const short* __restrict__ xT, const short* __restrict__ x1T,
    float* __restrict__ feat0, float* __restrict__ feat1,
    short* __restrict__ Eg0, short* __restrict__ Eg1,
    float* __restrict__ pu0, float* __restrict__ pu1)
{
    __shared__ short xs[12 * 2048];   // 48 KB
    __shared__ short hs[8 * 2048];    // 32 KB (256 k-rows x 64 n, B-fragment order)
    const int tid = threadIdx.x;
    const int wid = tid >> 6, lane = tid & 63;   // wid 0..7
    const int l15 = lane & 15, q = lane >> 4;
    const int bx = blockIdx.x, b = blockIdx.y;
    const int sc = bx >= 64;
    const int tile = sc ? bx - 64 : bx;
    const int N = sc ? 1024 : 4096;
    const int n0 = tile * 64;
    const short* XT = sc ? x1T : xT;
    const short* W1f = W1f_ + (size_t)sc * 491520;
    const float* B1p = B1p_ + sc * 1280;
    const short* W2af = W2af_ + (size_t)sc * 65536;
    const short* W2bf = W2bf_ + (size_t)sc * 98304;
    const float* fb2 = sc ? fb2_1 : fb2_0;
    const float* B2bp = B2bp_ + sc * 128;
    float* feat = (sc ? feat1 : feat0) + (long)b * 128 * N;
    short* Eg = (sc ? Eg1 : Eg0) + (long)b * 65 * N;
    float* pu = sc ? pu1 : pu0;
    const int npart = sc ? 16 : 64;

    // stage x tile [64 n x 384 k] into fragment-order LDS (512 threads)
    {
        const int n = tid >> 3;          // 0..63
        const int c0 = (tid & 7) * 6;    // 8 threads cover 48 c-groups
        const short* src = XT + ((long)b * N + n0 + n) * 384 + c0 * 8;
        const int jj = n >> 4, nl = n & 15;
        #pragma unroll
        for (int i = 0; i < 6; i++) {
            int c = c0 + i;
            int kc = c >> 2, qq = c & 3;
            *(short8*)(xs + kc * 2048 + jj * 512 + ((qq << 4) | nl) * 8) =
                *(const short8*)(src + i * 8);
        }
    }
    __syncthreads();

    floatx4 acc2[2][4];   // [0] = feat group wid, [1] = E group wid (wid<5)
    #pragma unroll
    for (int i = 0; i < 2; i++)
        #pragma unroll
        for (int j = 0; j < 4; j++) acc2[i][j] = floatx4{0.f, 0.f, 0.f, 0.f};

    auto phase2 = [&](int pc) {
        if (pc < 2) {
            const short* WA = W2af + (size_t)pc * 32768;
            short8 hb[2][4], wa[2];
            #pragma unroll
            for (int j = 0; j < 4; j++) hb[0][j] = *(short8*)(hs + j * 512 + lane * 8);
            wa[0] = *(const short8*)(WA + wid * 512 + lane * 8);
            #pragma unroll
            for (int kc2 = 0; kc2 < 8; kc2++) {
                short8 bfr[4];
                #pragma unroll
                for (int j = 0; j < 4; j++) bfr[j] = hb[kc2 & 1][j];
                short8 aF = wa[kc2 & 1];
                if (kc2 + 1 < 8) {
                    #pragma unroll
                    for (int j = 0; j < 4; j++)
                        hb[(kc2 + 1) & 1][j] = *(short8*)(hs + (kc2 + 1) * 2048 + j * 512 + lane * 8);
                    wa[(kc2 + 1) & 1] = *(const short8*)(WA + ((kc2 + 1) * 8 + wid) * 512 + lane * 8);
                }
                #pragma unroll
                for (int j = 0; j < 4; j++)
                    acc2[0][j] = __builtin_amdgcn_mfma_f32_16x16x32_bf16(aF, bfr[j], acc2[0][j], 0, 0, 0);
            }
        } else {
            if (wid >= 5) return;   // wave-uniform: E rows only on waves 0..4
            const short* WB = W2bf + (size_t)(pc - 2) * 32768;
            short8 hb[2][4], we[2];
            #pragma unroll
            for (int j = 0; j < 4; j++) hb[0][j] = *(short8*)(hs + j * 512 + lane * 8);
            we[0] = *(const short8*)(WB + wid * 512 + lane * 8);
            #pragma unroll
            for (int kc2 = 0; kc2 < 8; kc2++) {
                short8 bfr[4];
                #pragma unroll
                for (int j = 0; j < 4; j++) bfr[j] = hb[kc2 & 1][j];
                short8 aE = we[kc2 & 1];
                if (kc2 + 1 < 8) {
                    #pragma unroll
                    for (int j = 0; j < 4; j++)
                        hb[(kc2 + 1) & 1][j] = *(short8*)(hs + (kc2 + 1) * 2048 + j * 512 + lane * 8);
                    we[(kc2 + 1) & 1] = *(const short8*)(WB + ((kc2 + 1) * 8 + wid) * 512 + lane * 8);
                }
                #pragma unroll
                for (int j = 0; j < 4; j++)
                    acc2[1][j] = __builtin_amdgcn_mfma_f32_16x16x32_bf16(aE, bfr[j], acc2[1][j], 0, 0, 0);
            }
        }
    };

    for (int c = 0; c < 5; c++) {
        if (c > 0) phase2(c - 1);   // reads hs chunk c-1 (published at end of prev iter)
        // phase1: h rows c*256 + wid*32 .. +31; 2-deep global A prefetch
        floatx4 acc1[2][4];
        #pragma unroll
        for (int i = 0; i < 2; i++)
            #pragma unroll
            for (int j = 0; j < 4; j++) acc1[i][j] = floatx4{0.f, 0.f, 0.f, 0.f};
        const short* Wb = W1f + (long)c * 98304;
        short8 abuf[2][2];
        #pragma unroll
        for (int i = 0; i < 2; i++) {
            abuf[0][i] = *(const short8*)(Wb + (wid * 2 + i) * 512 + lane * 8);
            abuf[1][i] = *(const short8*)(Wb + (16 + wid * 2 + i) * 512 + lane * 8);
        }
        #pragma unroll
        for (int kc = 0; kc < 12; kc++) {
            short8 ac[2], bc[4];
            #pragma unroll
            for (int i = 0; i < 2; i++) ac[i] = abuf[kc & 1][i];
            #pragma unroll
            for (int j = 0; j < 4; j++) bc[j] = *(short8*)(xs + kc * 2048 + j * 512 + lane * 8);
            if (kc + 2 < 12) {
                #pragma unroll
                for (int i = 0; i < 2; i++)
                    abuf[kc & 1][i] = *(const short8*)(Wb + ((kc + 2) * 16 + wid * 2 + i) * 512 + lane * 8);
            }
            #pragma unroll
            for (int i = 0; i < 2; i++)
                #pragma unroll
                for (int j = 0; j < 4; j++)
                    acc1[i][j] = __builtin_amdgcn_mfma_f32_16x16x32_bf16(ac[i], bc[j], acc1[i][j], 0, 0, 0);
        }
        __syncthreads();   // hs readers (phase2 of chunk c-1) done
        // h-chunk -> hs (bias + relu + bf16 via cvt_pk), phase-2 B-fragment order
        #pragma unroll
        for (int i = 0; i < 2; i++) {
            const int qf = i * 2 + (q >> 1);
            const int e0 = 4 * (q & 1);
            const int mrow = c * 256 + wid * 32 + i * 16 + q * 4;
            float bw[4];
            #pragma unroll
            for (int rr = 0; rr < 4; rr++) bw[rr] = B1p[mrow + rr];
            #pragma unroll
            for (int j = 0; j < 4; j++) {
                float r0 = fmaxf(acc1[i][j][0] + bw[0], 0.f);
                float r1 = fmaxf(acc1[i][j][1] + bw[1], 0.f);
                float r2 = fmaxf(acc1[i][j][2] + bw[2], 0.f);
                float r3 = fmaxf(acc1[i][j][3] + bw[3], 0.f);
                unsigned lo = cvtpk2(r0, r1), hi = cvtpk2(r2, r3);
                unsigned long long pk = ((unsigned long long)hi << 32) | lo;
                *(unsigned long long*)(hs + wid * 2048 + j * 512 + ((qf << 4) | l15) * 8 + e0) = pk;
            }
        }
        __syncthreads();   // hs visible
    }
    phase2(4);

    // epilogue: feat (every wave owns rows wid*16 .. +15)
    {
        const int row0 = wid * 16 + q * 4;
        #pragma unroll
        for (int rr = 0; rr < 4; rr++) {
            float bv = fb2[row0 + rr];
            #pragma unroll
            for (int j = 0; j < 4; j++)
                feat[(long)(row0 + rr) * N + n0 + 16 * j + l15] = acc2[0][j][rr] + bv;
        }
    }
    __syncthreads();               // all phase2(4) hs reads done; reuse hs
    float* puld = (float*)hs;
    if (wid < 4) {
        // E rows wid*16 .. +15
        #pragma unroll
        for (int rr = 0; rr < 4; rr++) {
            int row = wid * 16 + q * 4 + rr;
            float bv = B2bp[row];
            float s = 0.f;
            #pragma unroll
            for (int j = 0; j < 4; j++) {
                float e = expf(acc2[1][j][rr] + bv);
                Eg[(long)row * N + n0 + 16 * j + l15] = f2bf(e);
                s += e;
            }
            s += __shfl_xor(s, 1); s += __shfl_xor(s, 2);
            s += __shfl_xor(s, 4); s += __shfl_xor(s, 8);
            if (l15 == 0) puld[row] = s;
        }
    } else if (wid == 4) {
        // dustbin row 64 only
        #pragma unroll
        for (int rr = 0; rr < 4; rr++) {
            int row = 64 + q * 4 + rr;
            bool valid = (row == 64);
            float bv = B2bp[64];
            float s = 0.f;
            #pragma unroll
            for (int j = 0; j < 4; j++) {
                float e = expf(acc2[1][j][rr] + bv);
                if (valid) {
                    Eg[(long)64 * N + n0 + 16 * j + l15] = f2bf(e);
                    s += e;
                }
            }
            s += __shfl_xor(s, 1); s += __shfl_xor(s, 2);
            s += __shfl_xor(s, 4); s += __shfl_xor(s, 8);
            if (valid && l15 == 0) puld[64] = s;
        }
    }
    __syncthreads();
    if (tid < 65)
        pu[((long)b * npart + tile) * 65 + tid] = puld[tid];
}

// ---------------- sk_step: 128-col chunks (640 blocks) ----------------
__global__ __launch_bounds__(256) void sk_step(
    const short* __restrict__ Eg0, const short* __restrict__ Eg1,
    const float* __restrict__ pin0, const float* __restrict__ pin1,
    float* __restrict__ pout0, float* __restrict__ pout1, int nin0, int nin1)
{
    __shared__ short Es[65 * 136];    // 17680 B
    __shared__ float evs[128];
    __shared__ float eus[65];
    const int t = threadIdx.x;
    const int bx = blockIdx.x, b = blockIdx.y;
    const int sc = bx >= 32;
    const int chunk = sc ? bx - 32 : bx;
    const int N = sc ? 1024 : 4096;
    const float invN = sc ? (1.0f / 1024.0f) : (1.0f / 4096.0f);
    const int n0 = chunk * 128;
    const short* Eb = (sc ? Eg1 : Eg0) + (long)b * 65 * N;
    const float* pin = sc ? pin1 : pin0;
    const int nin = sc ? nin1 : nin0;
    float* pout = sc ? pout1 : pout0;
    const int nout = sc ? 8 : 32;
    if (t < 65) {
        float s = 0.f;
        for (int ch = 0; ch < nin; ch++) s += pin[((long)b * nin + ch) * 65 + t];
        eus[t] = (1.0f / 65.0f) / s;
    }
    for (int it = t; it < 1040; it += 256) {
        int k = it >> 4, n8 = it & 15;
        *(short8*)(Es + k * 136 + n8 * 8) = *(const short8*)(Eb + (long)k * N + n0 + n8 * 8);
    }
    __syncthreads();
    if (t < 128) {
        float sv = 0.f;
        #pragma unroll 4
        for (int k = 0; k < 65; k++) sv += bf2f(Es[k * 136 + t]) * eus[k];
        evs[t] = invN / sv;
    }
    __syncthreads();
    const int wid = t >> 6, lane = t & 63;
    for (int k = wid; k < 65; k += 4) {
        const short* er = Es + k * 136 + lane * 2;
        float2 v2 = *(const float2*)&evs[lane * 2];
        float s = bf2f(er[0]) * v2.x + bf2f(er[1]) * v2.y;
        #pragma unroll
        for (int off = 32; off >= 1; off >>= 1) s += __shfl_xor(s, off);
        if (lane == 0) pout[((long)b * nout + chunk) * 65 + k] = s;
    }
}

// ---------------- sk_desc: 128-col chunks; eu; final v-step; desc partials via MFMA ----------------
__global__ __launch_bounds__(256) void sk_desc(
    const short* __restrict__ Eg0, const short* __restrict__ Eg1,
    const float* __restrict__ pin0, const float* __restrict__ pin1,
    const float* __restrict__ feat0, const float* __restrict__ feat1,
    float* __restrict__ part0, float* __restrict__ part1, int nin0, int nin1)
{
    __shared__ short Es[65 * 136];
    __shared__ float eus[65];
    __shared__ float evs[128];
    const int t = threadIdx.x;
    const int bx = blockIdx.x, b = blockIdx.y;
    const int sc = bx >= 32;
    const int chunk = sc ? bx - 32 : bx;
    const int N = sc ? 1024 : 4096;
    const float invN = sc ? (1.0f / 1024.0f) : (1.0f / 4096.0f);
    const int nch = sc ? 8 : 32;
    const int n0 = chunk * 128;
    const short* Eb = (sc ? Eg1 : Eg0) + (long)b * 65 * N;
    const float* pin = sc ? pin1 : pin0;
    const int nin = sc ? nin1 : nin0;
    const float* fb = (sc ? feat1 : feat0) + (long)b * 128 * N;
    float* part = sc ? part1 : part0;
    if (t < 65) {
        float s = 0.f;
        for (int ch = 0; ch < nin; ch++) s += pin[((long)b * nin + ch) * 65 + t];
        eus[t] = (1.0f / 65.0f) / s;
    }
    for (int it = t; it < 1040; it += 256) {
        int k = it >> 4, n8 = it & 15;
        *(short8*)(Es + k * 136 + n8 * 8) = *(const short8*)(Eb + (long)k * N + n0 + n8 * 8);
    }
    __syncthreads();
    if (t < 128) {
        float sv = 0.f;
        #pragma unroll 4
        for (int k = 0; k < 65; k++) sv += bf2f(Es[k * 136 + t]) * eus[k];
        evs[t] = invN / sv;
    }
    __syncthreads();
    const int wid = t >> 6, lane = t & 63;
    const int l15 = lane & 15, q = lane >> 4;
    float* pb = part + ((long)b * nch + chunk) * 8256;
    // P row-sum partials: eu[k] * sum_n E[k,n]*ev[n]
    for (int k = wid; k < 64; k += 4) {
        const short* er = Es + k * 136 + lane * 2;
        float2 v2 = *(const float2*)&evs[lane * 2];
        float s = bf2f(er[0]) * v2.x + bf2f(er[1]) * v2.y;
        #pragma unroll
        for (int off = 32; off >= 1; off >>= 1) s += __shfl_xor(s, off);
        if (lane == 0) pb[8192 + k] = s * eus[k];
    }
    // MFMA einsum: wave wid owns c rows wid*32..+31 (2 m-tiles), 64 k-cols (4 n-tiles)
    floatx4 acc[2][4];
    #pragma unroll
    for (int mt = 0; mt < 2; mt++)
        #pragma unroll
        for (int nt = 0; nt < 4; nt++) acc[mt][nt] = floatx4{0.f, 0.f, 0.f, 0.f};
    #pragma unroll
    for (int ks = 0; ks < 4; ks++) {
        float4 ev0 = *(const float4*)&evs[ks * 32 + q * 8];
        float4 ev1 = *(const float4*)&evs[ks * 32 + q * 8 + 4];
        float evq[8] = {ev0.x, ev0.y, ev0.z, ev0.w, ev1.x, ev1.y, ev1.z, ev1.w};
        short8 ah[2], al[2];
        #pragma unroll
        for (int mt = 0; mt < 2; mt++) {
            const float* fp = fb + (long)(wid * 32 + mt * 16 + l15) * N + n0 + ks * 32 + q * 8;
            float4 v0 = *(const float4*)fp;
            float4 v1 = *(const float4*)(fp + 4);
            float va[8] = {v0.x, v0.y, v0.z, v0.w, v1.x, v1.y, v1.z, v1.w};
            short hh[8], ll[8];
            #pragma unroll
            for (int e = 0; e < 8; e++) {
                float sv2 = va[e] * evq[e];
                short h = f2bf(sv2);
                hh[e] = h;
                ll[e] = f2bf(sv2 - bf2f(h));
            }
            ah[mt] = *(short8*)hh;
            al[mt] = *(short8*)ll;
        }
        #pragma unroll
        for (int nt = 0; nt < 4; nt++) {
            short8 bfr = *(short8*)(Es + (nt * 16 + l15) * 136 + ks * 32 + q * 8);
            #pragma unroll
            for (int mt = 0; mt < 2; mt++) {
                acc[mt][nt] = __builtin_amdgcn_mfma_f32_16x16x32_bf16(al[mt], bfr, acc[mt][nt], 0, 0, 0);
                acc[mt][nt] = __builtin_amdgcn_mfma_f32_16x16x32_bf16(ah[mt], bfr, acc[mt][nt], 0, 0, 0);
            }
        }
    }
    #pragma unroll
    for (int nt = 0; nt < 4; nt++) {
        float euk = eus[nt * 16 + l15];
        #pragma unroll
        for (int mt = 0; mt < 2; mt++)
            #pragma unroll
            for (int rr = 0; rr < 4; rr++)
                pb[(wid * 32 + mt * 16 + q * 4 + rr) * 64 + nt * 16 + l15] = acc[mt][nt][rr] * euk;
    }
}

// ---------------- dred1: chunk-sum + 1/rs + column-sq partials (128 blocks, full BW) ----------------
__global__ __launch_bounds__(256) void dred1(
    const float* __restrict__ part0, const float* __restrict__ part1,
    float* __restrict__ asum, float* __restrict__ colp2)
{
    __shared__ float rsv[2][64];
    __shared__ float sqs[256];
    const int j = blockIdx.x, b = blockIdx.y;
    const int t = threadIdx.x;
    // row-sum reciprocals (wave0: scale0, wave1: scale1)
    if (t < 128) {
        int s = t >> 6, k = t & 63;
        int nch = s ? 8 : 32;
        const float* pr = (s ? part1 : part0) + (long)b * nch * 8256 + 8192 + k;
        float rs = 0.f;
        for (int ch = 0; ch < nch; ch++) rs += pr[ch * 8256];
        rsv[s][k] = 1.0f / (rs + 1e-8f);
    }
    __syncthreads();
    const int kk = t & 63;
    #pragma unroll
    for (int s = 0; s < 2; s++) {
        const int nch = s ? 8 : 32;
        const float* pb = (s ? part1 : part0) + (long)b * nch * 8256 + j * 1024;
        float a[4];
        #pragma unroll
        for (int i = 0; i < 4; i++) a[i] = 0.f;
        for (int ch = 0; ch < nch; ch++) {
            const float* p = pb + (long)ch * 8256;
            #pragma unroll
            for (int i = 0; i < 4; i++) a[i] += p[t + 256 * i];
        }
        float rk = rsv[s][kk];
        #pragma unroll
        for (int i = 0; i < 4; i++) a[i] *= rk;
        float* as = asum + ((long)(b * 2 + s)) * 8192 + j * 1024;
        #pragma unroll
        for (int i = 0; i < 4; i++) as[t + 256 * i] = a[i];
        // column-sq partial: sum a^2 over this block's 16 c's for k = t&63
        float sq = a[0] * a[0] + a[1] * a[1] + a[2] * a[2] + a[3] * a[3];
        sqs[t] = sq;
        __syncthreads();
        if (t < 64)
            colp2[(((long)(b * 2 + s)) * 8 + j) * 64 + t] =
                sqs[t] + sqs[t + 64] + sqs[t + 128] + sqs[t + 192];
        __syncthreads();
    }
}

// ---------------- dred2: per-k norms + cross-scale mean + global norm ----------------
__global__ __launch_bounds__(1024) void dred2(
    const float* __restrict__ asum, const float* __restrict__ colp2,
    float* __restrict__ out, int b0)
{
    __shared__ float inv0[64], inv1[64];
    __shared__ float red[16];
    const int b = blockIdx.x;
    const int t = threadIdx.x;      // 0..1023
    const int wv = t >> 6, l = t & 63;
    if (t < 128) {
        int s = t >> 6, k = t & 63;
        float sq = 0.f;
        #pragma unroll
        for (int j = 0; j < 8; j++) sq += colp2[(((long)(b * 2 + s)) * 8 + j) * 64 + k];
        float iv = 1.0f / fmaxf(sqrtf(sq), 1e-12f);
        (s ? inv1 : inv0)[k] = iv;
    }
    __syncthreads();
    const int kk = t & 63;
    float i0 = inv0[kk], i1 = inv1[kk];
    const float* a0 = asum + ((long)(b * 2)) * 8192;
    const float* a1 = asum + ((long)(b * 2 + 1)) * 8192;
    float g[8];
    float ssum = 0.f;
    #pragma unroll
    for (int i = 0; i < 8; i++) {
        int e = t + 1024 * i;
        float v = (a0[e] * i0 + a1[e] * i1) * 0.5f;
        g[i] = v; ssum += v * v;
    }
    #pragma unroll
    for (int off = 32; off >= 1; off >>= 1) ssum += __shfl_xor(ssum, off);
    if (l == 0) red[wv] = ssum;
    __syncthreads();
    float tot = 0.f;
    #pragma unroll
    for (int w2 = 0; w2 < 16; w2++) tot += red[w2];
    float inv = 1.0f / fmaxf(sqrtf(tot), 1e-12f);
    float* o = out + (long)(b0 + b) * 8192;
    #pragma unroll
    for (int i = 0; i < 8; i++) o[t + 1024 * i] = g[i] * inv;
}

extern "C" void kernel_launch(void* const* d_in, const int* in_sizes, int n_in,
                              void* d_out, int out_size, void* d_ws, size_t ws_size,
                              hipStream_t stream)
{
    (void)in_sizes; (void)n_in; (void)out_size;
    const float* x = (const float*)d_in[0];
    WSet ws2[2];
    const float* fb2p[2];
    for (int s = 0; s < 2; s++) {
        int o = 1 + s * 12;
        ws2[s].fw1 = (const float*)d_in[o + 0];  ws2[s].fb1 = (const float*)d_in[o + 1];
        ws2[s].fw2 = (const float*)d_in[o + 2];  fb2p[s]    = (const float*)d_in[o + 3];
        ws2[s].sw1 = (const float*)d_in[o + 4];  ws2[s].sb1 = (const float*)d_in[o + 5];
        ws2[s].sw2 = (const float*)d_in[o + 6];  ws2[s].sb2 = (const float*)d_in[o + 7];
        ws2[s].dw1 = (const float*)d_in[o + 8];  ws2[s].db1 = (const float*)d_in[o + 9];
        ws2[s].dw2 = (const float*)d_in[o + 10]; ws2[s].db2 = (const float*)d_in[o + 11];
    }

    // part0/part1 alias xT/x1T (dead after fused_mlp reads them; stream-ordered safe).
    const size_t fixed = ((size_t)2*491520*2 + 2*65536*2 + 2*98304*2
                        + 2*1280*4 + 2*128*4) + (1 << 16);
    const size_t perb = (size_t)4096*384*2 + (size_t)1024*384*2
                      + (size_t)128*4096*4 + (size_t)128*1024*4
                      + (size_t)65*4096*2 + (size_t)65*1024*2
                      + (size_t)(64+16)*65*4 + (size_t)(32+8)*65*4
                      + (size_t)2*8192*4 + (size_t)2*8*64*4 + 8192;
    int CB = 4;
    const int cand[3] = {16, 8, 4};
    for (int ci = 0; ci < 3; ci++)
        if (fixed + (size_t)cand[ci] * perb <= ws_size) { CB = cand[ci]; break; }

    char* p = (char*)d_ws;
    auto alloc = [&](size_t bytes) -> char* {
        char* r = p; p += (bytes + 255) & ~(size_t)255; return r;
    };
    short* W1f   = (short*)alloc((size_t)2 * 491520 * 2);
    short* W2af  = (short*)alloc((size_t)2 * 65536 * 2);
    short* W2bf  = (short*)alloc((size_t)2 * 98304 * 2);
    float* B1p   = (float*)alloc((size_t)2 * 1280 * 4);
    float* B2bp  = (float*)alloc((size_t)2 * 128 * 4);
    short* xT    = (short*)alloc((size_t)CB * 4096 * 384 * 2);
    short* x1T   = (short*)alloc((size_t)CB * 1024 * 384 * 2);
    float* feat0 = (float*)alloc((size_t)CB * 128 * 4096 * 4);
    float* feat1 = (float*)alloc((size_t)CB * 128 * 1024 * 4);
    short* Eg0   = (short*)alloc((size_t)CB * 65 * 4096 * 2);
    short* Eg1   = (short*)alloc((size_t)CB * 65 * 1024 * 2);
    float* puA0  = (float*)alloc((size_t)CB * 64 * 65 * 4);
    float* puA1  = (float*)alloc((size_t)CB * 16 * 65 * 4);
    float* puB0  = (float*)alloc((size_t)CB * 32 * 65 * 4);
    float* puB1  = (float*)alloc((size_t)CB * 8 * 65 * 4);
    float* asum  = (float*)alloc((size_t)CB * 2 * 8192 * 4);
    float* colp2 = (float*)alloc((size_t)CB * 2 * 8 * 64 * 4);
    // aliases (xT: CB*3.15 MB >= CB*32*8256*4 = CB*1.06 MB; x1T: CB*0.79 >= CB*0.26)
    float* part0 = (float*)xT;
    float* part1 = (float*)x1T;

    wprep<<<dim3(2566, 2), 256, 0, stream>>>(ws2[0], ws2[1], W1f, W2af, W2bf, B1p, B2bp);
    for (int b0 = 0; b0 < 16; b0 += CB) {
        xprep<<<dim3(32, 6, CB), 256, 0, stream>>>(x + (size_t)b0 * 384 * 4096, xT, x1T);
        fused_mlp<<<dim3(80, CB), 512, 0, stream>>>(
            W1f, B1p, W2af, fb2p[0], fb2p[1], W2bf, B2bp,
            xT, x1T, feat0, feat1, Eg0, Eg1, puA0, puA1);
        sk_step<<<dim3(40, CB), 256, 0, stream>>>(Eg0, Eg1, puA0, puA1, puB0, puB1, 64, 16);
        sk_step<<<dim3(40, CB), 256, 0, stream>>>(Eg0, Eg1, puB0, puB1, puA0, puA1, 32, 8);
        sk_desc<<<dim3(40, CB), 256, 0, stream>>>(Eg0, Eg1, puA0, puA1,
                                                  feat0, feat1, part0, part1, 32, 8);
        dred1<<<dim3(8, CB), 256, 0, stream>>>(part0, part1, asum, colp2);
        dred2<<<dim3(CB), 1024, 0, stream>>>(asum, colp2, (float*)d_out, b0);
    }
}